// Round 6
// baseline (40.695 us; speedup 1.0000x reference)
//
#include <hip/hip_runtime.h>
#include <stdint.h>

typedef __attribute__((ext_vector_type(8))) short short8;
typedef __attribute__((ext_vector_type(4))) float f32x4;

#define CDIM 128
#define DDIM 64
#define RPB 8  // rows per block

__device__ __forceinline__ uint32_t pack2_bf16(float a, float b) {
  uint32_t ua = __float_as_uint(a);
  uint32_t ub = __float_as_uint(b);
  ua = (ua + 0x7FFFu + ((ua >> 16) & 1u)) >> 16;
  ub = (ub + 0x7FFFu + ((ub >> 16) & 1u)) >> 16;
  return ua | (ub << 16);
}

// Persistent blocks: 250 blocks x 8 rows. b,c stream via fire-and-forget
// global_load_lds into double-buffered raw LDS; counted vmcnt (never 0) +
// raw s_barrier keep next row's 16-load stream in flight across the whole
// current row's compute (T3/T4). exp/pack/MFMA identical to rounds 2-5
// (verified, absmax 0.0625). No max-stabilization (see prior rounds).
__global__ __launch_bounds__(256, 1) void logmvv_kernel(
    const float* __restrict__ a, const float* __restrict__ b,
    const float* __restrict__ c, float* __restrict__ out, int nt) {
  __shared__ __align__(16) float bRaw[2][CDIM * DDIM];  // 2 x 32 KB
  __shared__ __align__(16) float cRaw[2][CDIM * DDIM];  // 2 x 32 KB
  __shared__ __align__(16) uint16_t e2T[DDIM * CDIM];   // 16 KB, XOR-swizzled
  __shared__ __align__(16) float aLds[RPB * CDIM];      // 4 KB

  const int t = threadIdx.x;
  const int lane = t & 63;
  const int w = t >> 6;
  const int l15 = lane & 15;
  const int lq = lane >> 4;
  const int swz = (lane & 7) << 4;
  const int bid = blockIdx.x;
  const int row0 = bid * RPB;
  const int rows = (nt - row0 < RPB) ? (nt - row0) : RPB;

  // ---- prologue: stage a-block (1 instr/wave) + row0 b,c (16 instr/wave) ----
  __builtin_amdgcn_global_load_lds(
      (const __attribute__((address_space(1))) void*)(a + (size_t)row0 * CDIM +
                                                      w * 256 + lane * 4),
      (__attribute__((address_space(3))) void*)((char*)aLds + w * 1024), 16, 0, 0);

#define STAGE(ridx, buf)                                                        \
  {                                                                             \
    const float* bsrc = b + (size_t)(ridx) * (CDIM * DDIM);                     \
    const float* csrc = c + (size_t)(ridx) * (CDIM * DDIM);                     \
    _Pragma("unroll") for (int q = 0; q < 8; ++q) {                             \
      const int chunk = w * 8 + q; /* wave-uniform */                           \
      __builtin_amdgcn_global_load_lds(                                         \
          (const __attribute__((address_space(1))) void*)(bsrc + chunk * 256 +  \
                                                          lane * 4),            \
          (__attribute__((address_space(3))) void*)((char*)bRaw[buf] +          \
                                                    chunk * 1024),              \
          16, 0, 0);                                                            \
      __builtin_amdgcn_global_load_lds(                                         \
          (const __attribute__((address_space(1))) void*)(csrc + chunk * 256 +  \
                                                          lane * 4),            \
          (__attribute__((address_space(3))) void*)((char*)cRaw[buf] +          \
                                                    chunk * 1024),              \
          16, 0, 0);                                                            \
    }                                                                           \
  }

  STAGE(row0, 0);

  int cur = 0;
  const int colA = 16 * w + l15;
  char* e2b = (char*)e2T;

  for (int i = 0; i < rows; ++i) {
    const int row = row0 + i;
    const bool have_next = (i + 1 < rows);
    if (have_next) STAGE(row + 1, cur ^ 1);

    // Counted wait: retire row i's 16 DMA loads (+a), keep row i+1's 16 alive.
    // Queue (old->new): [stage(i) 16][stores(i-1) <=16][stage(i+1) 16].
    if (i == 0 && !have_next) {
      asm volatile("s_waitcnt vmcnt(0)" ::: "memory");
    } else if (i == 0 || !have_next) {
      asm volatile("s_waitcnt vmcnt(16)" ::: "memory");
    } else {
      asm volatile("s_waitcnt vmcnt(32)" ::: "memory");
    }
    __builtin_amdgcn_s_barrier();  // raw: no vmcnt(0) drain of the prefetch
    __builtin_amdgcn_sched_barrier(0);

    // ---- D1: exp(cRaw[cur]) -> bf16 -> swizzled e2T (col j=lane, 32 c's) ----
    const float* cr = cRaw[cur];
#pragma unroll
    for (int k = 0; k < 4; ++k) {
      float cvv[8];
#pragma unroll
      for (int p = 0; p < 8; ++p) cvv[p] = cr[(w * 32 + k * 8 + p) * DDIM + lane];
      const uint32_t r0 = pack2_bf16(__expf(cvv[0]), __expf(cvv[1]));
      const uint32_t r1 = pack2_bf16(__expf(cvv[2]), __expf(cvv[3]));
      const uint32_t r2 = pack2_bf16(__expf(cvv[4]), __expf(cvv[5]));
      const uint32_t r3 = pack2_bf16(__expf(cvv[6]), __expf(cvv[7]));
      *(uint4*)(e2b + lane * 256 + ((w * 64 + k * 16) ^ swz)) =
          make_uint4(r0, r1, r2, r3);
    }

    // ---- D2: afrag = exp(a + bRaw[cur]) in fragment layout ----
    const float* br = bRaw[cur];
    short8 afrag[4];
#pragma unroll
    for (int kk = 0; kk < 4; ++kk) {
      const int cbase = kk * 32 + lq * 8;
      float bv[8];
#pragma unroll
      for (int e = 0; e < 8; ++e)
        bv[e] = br[(cbase + e) * DDIM + colA] + aLds[i * CDIM + cbase + e];
      union { uint32_t u[4]; short8 s; } fr;
#pragma unroll
      for (int p = 0; p < 4; ++p)
        fr.u[p] = pack2_bf16(__expf(bv[2 * p]), __expf(bv[2 * p + 1]));
      afrag[kk] = fr.s;
    }

    asm volatile("s_waitcnt lgkmcnt(0)" ::: "memory");  // e2T writes visible
    __builtin_amdgcn_s_barrier();
    __builtin_amdgcn_sched_barrier(0);

    // ---- F: 16 x mfma_16x16x32_bf16 (B from swizzled e2T) ----
    f32x4 acc[4];
#pragma unroll
    for (int tj = 0; tj < 4; ++tj) acc[tj] = (f32x4){0.f, 0.f, 0.f, 0.f};
#pragma unroll
    for (int kk = 0; kk < 4; ++kk) {
      const int cb = kk * 64 + lq * 16;
#pragma unroll
      for (int tj = 0; tj < 4; ++tj) {
        const short8 bf =
            *(const short8*)(e2b + (16 * tj + l15) * 256 + (cb ^ swz));
        acc[tj] = __builtin_amdgcn_mfma_f32_16x16x32_bf16(afrag[kk], bf,
                                                          acc[tj], 0, 0, 0);
      }
    }

    // ---- G: out[i][j] = log(s); C/D layout col=lane&15, row=lq*4+rr ----
    float* op = out + (size_t)row * (DDIM * DDIM);
#pragma unroll
    for (int tj = 0; tj < 4; ++tj)
#pragma unroll
      for (int rr = 0; rr < 4; ++rr)
        op[(16 * w + lq * 4 + rr) * DDIM + 16 * tj + l15] = __logf(acc[tj][rr]);

    cur ^= 1;
  }
#undef STAGE
}

extern "C" void kernel_launch(void* const* d_in, const int* in_sizes, int n_in,
                              void* d_out, int out_size, void* d_ws, size_t ws_size,
                              hipStream_t stream) {
  const float* a = (const float*)d_in[0];
  const float* b = (const float*)d_in[1];
  const float* c = (const float*)d_in[2];
  float* out = (float*)d_out;
  const int nt = in_sizes[0] / CDIM;  // 2000 real rows; ref's pad rows sliced off
  const int grid = (nt + RPB - 1) / RPB;  // 250 persistent-ish blocks
  logmvv_kernel<<<grid, 256, 0, stream>>>(a, b, c, out, nt);
}

// Round 7
// 30.953 us; speedup vs baseline: 1.3148x; 1.3148x over previous
//
#include <hip/hip_runtime.h>
#include <stdint.h>

typedef __attribute__((ext_vector_type(8))) short short8;
typedef __attribute__((ext_vector_type(4))) float f32x4;

#define CDIM 128
#define DDIM 64

__device__ __forceinline__ uint32_t pack2_bf16(float a, float b) {
  uint32_t ua = __float_as_uint(a);
  uint32_t ub = __float_as_uint(b);
  ua = (ua + 0x7FFFu + ((ua >> 16) & 1u)) >> 16;
  ub = (ub + 0x7FFFu + ((ub >> 16) & 1u)) >> 16;
  return ua | (ub << 16);
}

// Inline-asm loads: compiler cannot re-chunk the stream or insert vmcnt(0).
#define GLD(dst, base, ofs)                                              \
  asm volatile("global_load_dword %0, %1, off offset:%2"                 \
               : "=v"(dst)                                               \
               : "v"(base), "n"(ofs))
#define GLDX4(dst, base, ofs)                                            \
  asm volatile("global_load_dwordx4 %0, %1, off offset:%2"               \
               : "=v"(dst)                                               \
               : "v"(base), "n"(ofs))
// Counted wait (AITER discipline: never 0 until the final chunk) + fence so
// VALU consumers cannot hoist above it (guide rule 18).
#define WAITV(n)                                                         \
  do {                                                                   \
    asm volatile("s_waitcnt vmcnt(" #n ")" ::: "memory");                \
    __builtin_amdgcn_sched_barrier(0);                                   \
  } while (0)

// 32-load half-chunk: b[c][16*tr + l15] for c = kko*32 + lq*8 + e.
// Per-lane base covers (lq*8)*64 + l15 floats; imm offset = e*256B + tr*64B.
#define ISSUE32(S, base, kko)                                            \
  do {                                                                   \
    _Pragma("unroll") for (int _tr = 0; _tr < 4; ++_tr)                  \
        _Pragma("unroll") for (int _e = 0; _e < 8; ++_e)                 \
            GLD(S[_tr * 8 + _e], (base) + (kko)*8192, _tr * 64 + _e * 256); \
  } while (0)

// One wave = one row; no LDS, no barriers. k-map c = kk*32 + lq*8 + e is the
// SAME bijection on A and B sides => contraction correct (verified r1-r6,
// absmax 0.0625). No max-stabilization (log∘sum∘exp identity; N(0,1) inputs).
__global__ __launch_bounds__(256, 2) void logmvv_kernel(
    const float* __restrict__ a, const float* __restrict__ b,
    const float* __restrict__ c, float* __restrict__ out, int nt) {
  const int lane = threadIdx.x & 63;
  const int w = threadIdx.x >> 6;
  const int row = blockIdx.x * 4 + w;
  if (row >= nt) return;
  const int l15 = lane & 15;
  const int lq = lane >> 4;

  const uint64_t aB = (uint64_t)(a + (size_t)row * CDIM) + (uint64_t)(lq * 32);
  const uint64_t bB =
      (uint64_t)(b + (size_t)row * (CDIM * DDIM)) + (uint64_t)(lq * 2048 + l15 * 4);
  const uint64_t cB =
      (uint64_t)(c + (size_t)row * (CDIM * DDIM)) + (uint64_t)(lq * 2048 + l15 * 4);

  // ---- prologue: a (8 x dwordx4 = 32 floats), b0(32), c0(32) in flight ----
  f32x4 ar[8];
#pragma unroll
  for (int kk = 0; kk < 4; ++kk) {
    GLDX4(ar[kk * 2 + 0], aB, 0 + 128 * kk);
    GLDX4(ar[kk * 2 + 1], aB, 16 + 128 * kk);
  }
  float bs0[32], bs1[32], cs0[32], cs1[32];
  ISSUE32(bs0, bB, 0);
  ISSUE32(cs0, cB, 0);

  f32x4 acc[4][4];
#pragma unroll
  for (int tr = 0; tr < 4; ++tr)
#pragma unroll
    for (int tj = 0; tj < 4; ++tj) acc[tr][tj] = (f32x4){0.f, 0.f, 0.f, 0.f};

#define AFRAG(af, S, kk)                                                   \
  do {                                                                     \
    _Pragma("unroll") for (int tr = 0; tr < 4; ++tr) {                     \
      union { uint32_t u[4]; short8 s; } fr;                               \
      _Pragma("unroll") for (int p = 0; p < 4; ++p) {                      \
        const float x0 = ar[(kk)*2 + (p >> 1)][(2 * p) & 3] + S[tr * 8 + 2 * p]; \
        const float x1 = ar[(kk)*2 + (p >> 1)][(2 * p + 1) & 3] + S[tr * 8 + 2 * p + 1]; \
        fr.u[p] = pack2_bf16(__expf(x0), __expf(x1));                      \
      }                                                                    \
      af[tr] = fr.s;                                                       \
    }                                                                      \
  } while (0)

#define BFRAG_MFMA(af, S)                                                  \
  do {                                                                     \
    _Pragma("unroll") for (int tj = 0; tj < 4; ++tj) {                     \
      union { uint32_t u[4]; short8 s; } fr;                               \
      _Pragma("unroll") for (int p = 0; p < 4; ++p)                        \
        fr.u[p] = pack2_bf16(__expf(S[tj * 8 + 2 * p]),                    \
                             __expf(S[tj * 8 + 2 * p + 1]));               \
      _Pragma("unroll") for (int tr = 0; tr < 4; ++tr)                     \
        acc[tr][tj] = __builtin_amdgcn_mfma_f32_16x16x32_bf16(             \
            af[tr], fr.s, acc[tr][tj], 0, 0, 0);                           \
    }                                                                      \
  } while (0)

  short8 af[4];
  // kk0: queue [A(8) b0(32) c0(32)]
  WAITV(32);            // A+b0 ready; c0 outstanding
  ISSUE32(bs1, bB, 1);  // out: c0,b1 = 64
  AFRAG(af, bs0, 0);
  WAITV(32);            // c0 ready; b1 outstanding
  ISSUE32(cs1, cB, 1);  // out: b1,c1 = 64
  BFRAG_MFMA(af, cs0);
  // kk1
  WAITV(32);            // b1 ready; c1 outstanding
  ISSUE32(bs0, bB, 2);
  AFRAG(af, bs1, 1);
  WAITV(32);            // c1 ready; b2 outstanding
  ISSUE32(cs0, cB, 2);
  BFRAG_MFMA(af, cs1);
  // kk2
  WAITV(32);            // b2 ready; c2 outstanding
  ISSUE32(bs1, bB, 3);
  AFRAG(af, bs0, 2);
  WAITV(32);            // c2 ready; b3 outstanding
  ISSUE32(cs1, cB, 3);
  BFRAG_MFMA(af, cs0);
  // kk3 (final: drain)
  WAITV(32);            // b3 ready; c3 outstanding
  AFRAG(af, bs1, 3);
  WAITV(0);             // c3 ready
  BFRAG_MFMA(af, cs1);

  // ---- epilogue: out[i][j] = log(s); C/D col=l15, row=lq*4+rr per tile ----
  float* op = out + (size_t)row * (DDIM * DDIM);
#pragma unroll
  for (int tr = 0; tr < 4; ++tr)
#pragma unroll
    for (int tj = 0; tj < 4; ++tj)
#pragma unroll
      for (int rr = 0; rr < 4; ++rr)
        op[(16 * tr + lq * 4 + rr) * DDIM + 16 * tj + l15] =
            __logf(acc[tr][tj][rr]);
#undef AFRAG
#undef BFRAG_MFMA
}

extern "C" void kernel_launch(void* const* d_in, const int* in_sizes, int n_in,
                              void* d_out, int out_size, void* d_ws, size_t ws_size,
                              hipStream_t stream) {
  const float* a = (const float*)d_in[0];
  const float* b = (const float*)d_in[1];
  const float* c = (const float*)d_in[2];
  float* out = (float*)d_out;
  const int nt = in_sizes[0] / CDIM;        // 2000 real rows
  const int grid = (nt + 3) / 4;            // 4 rows (waves) per 256-thr block
  logmvv_kernel<<<grid, 256, 0, stream>>>(a, b, c, out, nt);
}